// Round 1
// baseline (130.147 us; speedup 1.0000x reference)
//
#include <hip/hip_runtime.h>

#define BB 64
#define SS 512
#define HH 1024
#define SUP 100
#define KFS 5
#define NCLS 3

// ---------------- K1: partial pooling (sum over s-chunks) ----------------
// grid 256 blocks: b = blk>>2, seg = blk&3 (128 s each). 256 thr, float4 over H.
__global__ void pool_partial(const float* __restrict__ hs, float* __restrict__ part) {
    int blk = blockIdx.x;
    int b   = blk >> 2;
    int seg = blk & 3;
    int t   = threadIdx.x;           // 0..255 -> float4 index over H
    const float4* src = (const float4*)(hs + (size_t)b * SS * HH);
    float4 acc = make_float4(0.f, 0.f, 0.f, 0.f);
    int s0 = seg * 128;
    for (int s = s0; s < s0 + 128; ++s) {
        float4 v = src[s * 256 + t];
        acc.x += v.x; acc.y += v.y; acc.z += v.z; acc.w += v.w;
    }
    ((float4*)part)[(seg * BB + b) * 256 + t] = acc;
}

// ---------------- K2: reduce partials, scale by 1/512 ----------------
__global__ void pool_reduce(const float* __restrict__ part, float* __restrict__ pooled) {
    int b = blockIdx.x;
    int t = threadIdx.x;
    float4 acc = make_float4(0.f, 0.f, 0.f, 0.f);
    for (int seg = 0; seg < 4; ++seg) {
        float4 v = ((const float4*)part)[(seg * BB + b) * 256 + t];
        acc.x += v.x; acc.y += v.y; acc.z += v.z; acc.w += v.w;
    }
    const float inv = 1.0f / 512.0f;
    acc.x *= inv; acc.y *= inv; acc.z *= inv; acc.w *= inv;
    ((float4*)pooled)[b * 256 + t] = acc;
}

// ---------------- K3: generic out[m,n] = A[m,:] . W[n,:] + bias[n] ----------------
// A: [64, 1024]; W: [N, 1024]; out: [64, N]. 16x16 tile per 256-thread block.
// grid.x = N/16, grid.y = 4.
__global__ void linear_nt(const float* __restrict__ A, const float* __restrict__ W,
                          const float* __restrict__ bias, float* __restrict__ out, int N) {
    __shared__ __align__(16) float As[16][68];   // pad 68: rows 16B-aligned, 2-way max conflict
    __shared__ __align__(16) float Bs[16][68];
    int n0 = blockIdx.x * 16, m0 = blockIdx.y * 16;
    int t  = threadIdx.x;
    int lr = t >> 4;        // load row 0..15
    int lc = t & 15;        // load float4 col 0..15
    int tm = t >> 4, tn = t & 15;
    float acc = 0.f;
    for (int kc = 0; kc < HH; kc += 64) {
        float4 a = *(const float4*)(A + (size_t)(m0 + lr) * HH + kc + lc * 4);
        float4 w = *(const float4*)(W + (size_t)(n0 + lr) * HH + kc + lc * 4);
        *(float4*)&As[lr][lc * 4] = a;
        *(float4*)&Bs[lr][lc * 4] = w;
        __syncthreads();
#pragma unroll
        for (int k = 0; k < 64; ++k)
            acc += As[tm][k] * Bs[tn][k];
        __syncthreads();
    }
    out[(size_t)(m0 + tm) * N + n0 + tn] = acc + bias[n0 + tn];
}

// ---------------- K4: sims + top5 + softmax + onehot scatter + broadcast ----------------
// one block per b, 256 threads (4 waves).
__global__ void fewshot(const float* __restrict__ pooled,
                        const float* __restrict__ supF,
                        const int* __restrict__ labels,
                        const int* __restrict__ supL,
                        float* __restrict__ out_fsp) {
    __shared__ float ps[HH];
    __shared__ float sims[SUP];
    __shared__ float pred[NCLS];
    int b = blockIdx.x, t = threadIdx.x;
    ((float4*)ps)[t] = ((const float4*)(pooled + (size_t)b * HH))[t];
    __syncthreads();

    int wave = t >> 6, lane = t & 63;
    for (int j = wave; j < SUP; j += 4) {
        // supF row j<64 was overwritten by pooled[j]; j>=64 keeps original support row
        const float* row = (j < BB) ? (pooled + (size_t)j * HH)
                                    : (supF + (size_t)j * HH);
        float s = 0.f;
#pragma unroll
        for (int q = 0; q < 16; ++q) {
            int h = lane + q * 64;
            s += ps[h] * row[h];
        }
        for (int off = 32; off; off >>= 1) s += __shfl_down(s, off);
        if (lane == 0) sims[j] = s;
    }
    __syncthreads();

    if (t == 0) {
        float vals[KFS]; int idx[KFS];
        for (int i = 0; i < KFS; ++i) {
            float best = -3.4e38f; int bi = 0;
            for (int j = 0; j < SUP; ++j) {
                bool taken = false;
                for (int p = 0; p < i; ++p) taken = taken || (idx[p] == j);
                if (!taken && sims[j] > best) { best = sims[j]; bi = j; }
            }
            vals[i] = best; idx[i] = bi;
        }
        float mx = vals[0];
        for (int i = 1; i < KFS; ++i) mx = fmaxf(mx, vals[i]);
        float e[KFS], sum = 0.f;
        for (int i = 0; i < KFS; ++i) { e[i] = __expf(vals[i] - mx); sum += e[i]; }
        float p0 = 0.f, p1 = 0.f, p2 = 0.f;
        for (int i = 0; i < KFS; ++i) {
            int j = idx[i];
            int lab = (j < BB) ? labels[j] : supL[j];
            float wv = e[i] / sum;
            if (lab == 0) p0 += wv;
            else if (lab == 1) p1 += wv;
            else if (lab == 2) p2 += wv;   // out-of-range label -> contributes nothing
        }
        pred[0] = p0; pred[1] = p1; pred[2] = p2;
    }
    __syncthreads();

    float p[NCLS] = {pred[0], pred[1], pred[2]};
    for (int i = t; i < SS * NCLS; i += 256) {
        int c = i - (i / NCLS) * NCLS;
        out_fsp[(size_t)b * SS * NCLS + i] = p[c];
    }
}

extern "C" void kernel_launch(void* const* d_in, const int* in_sizes, int n_in,
                              void* d_out, int out_size, void* d_ws, size_t ws_size,
                              hipStream_t stream) {
    const float* hs    = (const float*)d_in[0];   // [64,512,1024]
    const int*   lab   = (const int*)  d_in[1];   // [64]
    const float* supF  = (const float*)d_in[2];   // [100,1024]
    const int*   supL  = (const int*)  d_in[3];   // [100]
    const float* W_sim = (const float*)d_in[4];   // [128,1024]
    const float* b_sim = (const float*)d_in[5];
    const float* W_div = (const float*)d_in[6];   // [128,1024]
    const float* b_div = (const float*)d_in[7];
    const float* W_met = (const float*)d_in[8];   // [1024,1024]
    const float* b_met = (const float*)d_in[9];
    const float* W_con = (const float*)d_in[10];  // [256,1024]
    const float* b_con = (const float*)d_in[11];

    float* out = (float*)d_out;
    float* out_fsp  = out;                 // [64,512,3]  = 98304
    float* out_sim  = out + 98304;         // [64,128]    = 8192
    float* out_div  = out + 106496;        // [64,128]    = 8192
    float* out_con  = out + 114688;        // [64,256]    = 16384

    float* ws       = (float*)d_ws;
    float* part     = ws;                  // 4*64*1024 = 262144 floats
    float* pooled   = ws + 262144;         // 64*1024   = 65536
    float* meta_mean= ws + 262144 + 65536; // 64*1024   = 65536

    pool_partial<<<256, 256, 0, stream>>>(hs, part);
    pool_reduce <<< BB, 256, 0, stream>>>(part, pooled);

    dim3 gsim(128 / 16, 4);
    linear_nt<<<gsim, 256, 0, stream>>>(pooled, W_sim, b_sim, out_sim, 128);
    dim3 gdiv(128 / 16, 4);
    linear_nt<<<gdiv, 256, 0, stream>>>(pooled, W_div, b_div, out_div, 128);
    dim3 gmet(1024 / 16, 4);
    linear_nt<<<gmet, 256, 0, stream>>>(pooled, W_met, b_met, meta_mean, 1024);
    dim3 gcon(256 / 16, 4);
    linear_nt<<<gcon, 256, 0, stream>>>(meta_mean, W_con, b_con, out_con, 256);

    fewshot<<<BB, 256, 0, stream>>>(pooled, supF, lab, supL, out_fsp);
}

// Round 2
// 84.306 us; speedup vs baseline: 1.5437x; 1.5437x over previous
//
#include <hip/hip_runtime.h>

#define BB 64
#define SS 512
#define HH 1024
#define SUP 100
#define KFS 5
#define NCLS 3
#define SEG 16   // s-segments for pooling: 1024 blocks, 4 wg/CU

// ---------------- K1: partial pooling (sum over s-chunks) ----------------
// grid = BB*SEG blocks: b = blk>>4, seg = blk&15 (32 s each). 256 thr, float4 over H.
__global__ void pool_partial(const float* __restrict__ hs, float* __restrict__ part) {
    int blk = blockIdx.x;
    int b   = blk >> 4;
    int seg = blk & (SEG - 1);
    int t   = threadIdx.x;           // 0..255 -> float4 index over H
    const float4* src = (const float4*)(hs + (size_t)b * SS * HH);
    float4 acc = make_float4(0.f, 0.f, 0.f, 0.f);
    int s0 = seg * (SS / SEG);
    for (int s = s0; s < s0 + (SS / SEG); ++s) {
        float4 v = src[s * 256 + t];
        acc.x += v.x; acc.y += v.y; acc.z += v.z; acc.w += v.w;
    }
    ((float4*)part)[(seg * BB + b) * 256 + t] = acc;
}

// ---------------- K2: reduce partials, scale by 1/512 ----------------
__global__ void pool_reduce(const float* __restrict__ part, float* __restrict__ pooled) {
    int b = blockIdx.x;
    int t = threadIdx.x;
    float4 acc = make_float4(0.f, 0.f, 0.f, 0.f);
    for (int seg = 0; seg < SEG; ++seg) {
        float4 v = ((const float4*)part)[(seg * BB + b) * 256 + t];
        acc.x += v.x; acc.y += v.y; acc.z += v.z; acc.w += v.w;
    }
    const float inv = 1.0f / 512.0f;
    acc.x *= inv; acc.y *= inv; acc.z *= inv; acc.w *= inv;
    ((float4*)pooled)[b * 256 + t] = acc;
}

// ---------------- shared 16x16-tile linear body ----------------
// out[m,n] = A[m,:] . W[n,:] + bias[n], A:[64,HH], W:[N,HH]
__device__ __forceinline__ void linear_tile(const float* __restrict__ A,
                                            const float* __restrict__ W,
                                            const float* __restrict__ bias,
                                            float* __restrict__ out, int N,
                                            int m0, int n0, int t,
                                            float (*As)[68], float (*Bs)[68]) {
    int lr = t >> 4;        // load row 0..15
    int lc = t & 15;        // load float4 col 0..15
    int tm = t >> 4, tn = t & 15;
    float acc = 0.f;
    for (int kc = 0; kc < HH; kc += 64) {
        float4 a = *(const float4*)(A + (size_t)(m0 + lr) * HH + kc + lc * 4);
        float4 w = *(const float4*)(W + (size_t)(n0 + lr) * HH + kc + lc * 4);
        *(float4*)&As[lr][lc * 4] = a;
        *(float4*)&Bs[lr][lc * 4] = w;
        __syncthreads();
#pragma unroll
        for (int k = 0; k < 64; ++k)
            acc += As[tm][k] * Bs[tn][k];
        __syncthreads();
    }
    out[(size_t)(m0 + tm) * N + n0 + tn] = acc + bias[n0 + tn];
}

// ---------------- K3: batched {sim, div, meta_mean} linears ----------------
// grid (80, 4): bx<8 sim tiles, bx<16 div tiles, else meta tiles. by = m-tile.
__global__ void linears3(const float* __restrict__ pooled,
                         const float* __restrict__ W_sim, const float* __restrict__ b_sim,
                         const float* __restrict__ W_div, const float* __restrict__ b_div,
                         const float* __restrict__ W_met, const float* __restrict__ b_met,
                         float* __restrict__ out_sim, float* __restrict__ out_div,
                         float* __restrict__ meta_mean) {
    __shared__ __align__(16) float As[16][68];
    __shared__ __align__(16) float Bs[16][68];
    int bx = blockIdx.x;
    const float *W, *bias; float* out; int N, n0;
    if (bx < 8)       { W = W_sim; bias = b_sim; out = out_sim;  N = 128;  n0 = bx * 16; }
    else if (bx < 16) { W = W_div; bias = b_div; out = out_div;  N = 128;  n0 = (bx - 8) * 16; }
    else              { W = W_met; bias = b_met; out = meta_mean; N = 1024; n0 = (bx - 16) * 16; }
    linear_tile(pooled, W, bias, out, N, blockIdx.y * 16, n0, threadIdx.x, As, Bs);
}

// ---------------- K4: con GEMM tiles + fewshot, fused ----------------
// blocks 0..63: fewshot for b = blk. blocks 64..127: con tile id = blk-64
// (m-tile = id>>4 in 0..3, n-tile = id&15 in 0..15).
__global__ void tail4(const float* __restrict__ meta_mean,
                      const float* __restrict__ W_con, const float* __restrict__ b_con,
                      float* __restrict__ out_con,
                      const float* __restrict__ pooled,
                      const float* __restrict__ supF,
                      const int* __restrict__ labels,
                      const int* __restrict__ supL,
                      float* __restrict__ out_fsp) {
    __shared__ __align__(16) float As[16][68];
    __shared__ __align__(16) float Bs[16][68];
    __shared__ float ps[HH];
    __shared__ float sims[SUP];
    __shared__ float pred[NCLS];
    int blk = blockIdx.x, t = threadIdx.x;

    if (blk >= BB) {
        int id = blk - BB;
        linear_tile(meta_mean, W_con, b_con, out_con, 256,
                    (id >> 4) * 16, (id & 15) * 16, t, As, Bs);
        return;
    }

    int b = blk;
    ((float4*)ps)[t] = ((const float4*)(pooled + (size_t)b * HH))[t];
    __syncthreads();

    int wave = t >> 6, lane = t & 63;
    for (int j = wave; j < SUP; j += 4) {
        // supF row j<64 was overwritten by pooled[j]; j>=64 keeps original support row
        const float* row = (j < BB) ? (pooled + (size_t)j * HH)
                                    : (supF + (size_t)j * HH);
        float s = 0.f;
#pragma unroll
        for (int q = 0; q < 16; ++q) {
            int h = lane + q * 64;
            s += ps[h] * row[h];
        }
        for (int off = 32; off; off >>= 1) s += __shfl_down(s, off);
        if (lane == 0) sims[j] = s;
    }
    __syncthreads();

    if (t == 0) {
        float vals[KFS]; int idx[KFS];
        for (int i = 0; i < KFS; ++i) {
            float best = -3.4e38f; int bi = 0;
            for (int j = 0; j < SUP; ++j) {
                bool taken = false;
                for (int p = 0; p < i; ++p) taken = taken || (idx[p] == j);
                if (!taken && sims[j] > best) { best = sims[j]; bi = j; }
            }
            vals[i] = best; idx[i] = bi;
        }
        float mx = vals[0];
        for (int i = 1; i < KFS; ++i) mx = fmaxf(mx, vals[i]);
        float e[KFS], sum = 0.f;
        for (int i = 0; i < KFS; ++i) { e[i] = __expf(vals[i] - mx); sum += e[i]; }
        float p0 = 0.f, p1 = 0.f, p2 = 0.f;
        for (int i = 0; i < KFS; ++i) {
            int j = idx[i];
            int lab = (j < BB) ? labels[j] : supL[j];
            float wv = e[i] / sum;
            if (lab == 0) p0 += wv;
            else if (lab == 1) p1 += wv;
            else if (lab == 2) p2 += wv;   // out-of-range label -> contributes nothing
        }
        pred[0] = p0; pred[1] = p1; pred[2] = p2;
    }
    __syncthreads();

    float p[NCLS] = {pred[0], pred[1], pred[2]};
    for (int i = t; i < SS * NCLS; i += 256) {
        int c = i - (i / NCLS) * NCLS;
        out_fsp[(size_t)b * SS * NCLS + i] = p[c];
    }
}

extern "C" void kernel_launch(void* const* d_in, const int* in_sizes, int n_in,
                              void* d_out, int out_size, void* d_ws, size_t ws_size,
                              hipStream_t stream) {
    const float* hs    = (const float*)d_in[0];   // [64,512,1024]
    const int*   lab   = (const int*)  d_in[1];   // [64]
    const float* supF  = (const float*)d_in[2];   // [100,1024]
    const int*   supL  = (const int*)  d_in[3];   // [100]
    const float* W_sim = (const float*)d_in[4];   // [128,1024]
    const float* b_sim = (const float*)d_in[5];
    const float* W_div = (const float*)d_in[6];   // [128,1024]
    const float* b_div = (const float*)d_in[7];
    const float* W_met = (const float*)d_in[8];   // [1024,1024]
    const float* b_met = (const float*)d_in[9];
    const float* W_con = (const float*)d_in[10];  // [256,1024]
    const float* b_con = (const float*)d_in[11];

    float* out = (float*)d_out;
    float* out_fsp  = out;                 // [64,512,3]  = 98304
    float* out_sim  = out + 98304;         // [64,128]    = 8192
    float* out_div  = out + 106496;        // [64,128]    = 8192
    float* out_con  = out + 114688;        // [64,256]    = 16384

    float* ws       = (float*)d_ws;
    float* part     = ws;                          // SEG*64*1024 = 1M floats (4 MB)
    float* pooled   = ws + SEG * BB * HH;          // 64*1024
    float* meta_mean= pooled + BB * HH;            // 64*1024

    pool_partial<<<BB * SEG, 256, 0, stream>>>(hs, part);
    pool_reduce <<<BB,       256, 0, stream>>>(part, pooled);
    linears3<<<dim3(80, 4), 256, 0, stream>>>(pooled, W_sim, b_sim, W_div, b_div,
                                              W_met, b_met, out_sim, out_div, meta_mean);
    tail4<<<128, 256, 0, stream>>>(meta_mean, W_con, b_con, out_con,
                                   pooled, supF, lab, supL, out_fsp);
}

// Round 3
// 83.139 us; speedup vs baseline: 1.5654x; 1.0140x over previous
//
#include <hip/hip_runtime.h>

#define BB 64
#define SS 512
#define HH 1024
#define SUP 100
#define KFS 5
#define NCLS 3
#define SEG 32            // s-segments for pooling: 2048 blocks, 8 wg/CU
#define KSPLIT 8          // K-split for GEMMs
#define KB (HH / KSPLIT)  // 128 K per block
#define KC 32             // K staged per LDS chunk
#define ASLD 68           // LDS row pad: 68*4=272 B (16B-aligned rows, 2-way max conflict)

// ---------------- K1: partial pooling ----------------
__global__ void pool_partial(const float* __restrict__ hs, float* __restrict__ part) {
    int blk = blockIdx.x;
    int b   = blk >> 5;
    int seg = blk & (SEG - 1);
    int t   = threadIdx.x;
    const float4* src = (const float4*)(hs + (size_t)b * SS * HH);
    float4 acc = make_float4(0.f, 0.f, 0.f, 0.f);
    int s0 = seg * (SS / SEG);
#pragma unroll
    for (int s = s0; s < s0 + (SS / SEG); ++s) {
        float4 v = src[s * 256 + t];
        acc.x += v.x; acc.y += v.y; acc.z += v.z; acc.w += v.w;
    }
    ((float4*)part)[(seg * BB + b) * 256 + t] = acc;
}

// ---------------- K2: reduce partials, scale by 1/512 ----------------
__global__ void pool_reduce(const float* __restrict__ part, float* __restrict__ pooled) {
    int b = blockIdx.x;
    int t = threadIdx.x;
    float4 acc = make_float4(0.f, 0.f, 0.f, 0.f);
    for (int seg = 0; seg < SEG; ++seg) {
        float4 v = ((const float4*)part)[(seg * BB + b) * 256 + t];
        acc.x += v.x; acc.y += v.y; acc.z += v.z; acc.w += v.w;
    }
    const float inv = 1.0f / 512.0f;
    acc.x *= inv; acc.y *= inv; acc.z *= inv; acc.w *= inv;
    ((float4*)pooled)[b * 256 + t] = acc;
}

// ---------------- register-tiled 64x64 partial GEMM body ----------------
// partOut[ks][m][n0..n0+63] += A[m, k0:k0+KB] . W[n, k0:k0+KB]   (no bias)
// 256 threads, 4x4 acc per thread. As/Bs transposed: As[k][m].
__device__ __forceinline__ void gemm64_partial(const float* __restrict__ A,
                                               const float* __restrict__ W,
                                               float* __restrict__ partOut, int N,
                                               int n0, int k0, int ks, int t,
                                               float (*As)[ASLD], float (*Bs)[ASLD]) {
    int tm = t >> 4, tn = t & 15;
    int lr = t >> 2, lq = t & 3;     // stage: row 0..63, quad 0..3
    float acc[4][4] = {};
    for (int kc = 0; kc < KB; kc += KC) {
        int ka = k0 + kc + lq * 4;
        float4 a0 = *(const float4*)(A + (size_t)lr * HH + ka);
        float4 a1 = *(const float4*)(A + (size_t)lr * HH + ka + 16);
        float4 w0 = *(const float4*)(W + (size_t)(n0 + lr) * HH + ka);
        float4 w1 = *(const float4*)(W + (size_t)(n0 + lr) * HH + ka + 16);
        As[lq * 4 + 0][lr] = a0.x; As[lq * 4 + 1][lr] = a0.y;
        As[lq * 4 + 2][lr] = a0.z; As[lq * 4 + 3][lr] = a0.w;
        As[16 + lq * 4 + 0][lr] = a1.x; As[16 + lq * 4 + 1][lr] = a1.y;
        As[16 + lq * 4 + 2][lr] = a1.z; As[16 + lq * 4 + 3][lr] = a1.w;
        Bs[lq * 4 + 0][lr] = w0.x; Bs[lq * 4 + 1][lr] = w0.y;
        Bs[lq * 4 + 2][lr] = w0.z; Bs[lq * 4 + 3][lr] = w0.w;
        Bs[16 + lq * 4 + 0][lr] = w1.x; Bs[16 + lq * 4 + 1][lr] = w1.y;
        Bs[16 + lq * 4 + 2][lr] = w1.z; Bs[16 + lq * 4 + 3][lr] = w1.w;
        __syncthreads();
#pragma unroll
        for (int k = 0; k < KC; ++k) {
            float4 a4 = *(const float4*)&As[k][tm * 4];
            float4 b4 = *(const float4*)&Bs[k][tn * 4];
            acc[0][0] += a4.x * b4.x; acc[0][1] += a4.x * b4.y;
            acc[0][2] += a4.x * b4.z; acc[0][3] += a4.x * b4.w;
            acc[1][0] += a4.y * b4.x; acc[1][1] += a4.y * b4.y;
            acc[1][2] += a4.y * b4.z; acc[1][3] += a4.y * b4.w;
            acc[2][0] += a4.z * b4.x; acc[2][1] += a4.z * b4.y;
            acc[2][2] += a4.z * b4.z; acc[2][3] += a4.z * b4.w;
            acc[3][0] += a4.w * b4.x; acc[3][1] += a4.w * b4.y;
            acc[3][2] += a4.w * b4.z; acc[3][3] += a4.w * b4.w;
        }
        __syncthreads();
    }
#pragma unroll
    for (int i = 0; i < 4; ++i) {
        float4 o = make_float4(acc[i][0], acc[i][1], acc[i][2], acc[i][3]);
        *(float4*)(partOut + ((size_t)ks * 64 + tm * 4 + i) * N + n0 + tn * 4) = o;
    }
}

// ---------------- K3: partial GEMMs for sim/div/meta ----------------
// grid 160: [0,16) sim, [16,32) div, [32,160) meta. id: nt = id>>3, ks = id&7.
__global__ void lin_partial(const float* __restrict__ pooled,
                            const float* __restrict__ W_sim,
                            const float* __restrict__ W_div,
                            const float* __restrict__ W_met,
                            float* __restrict__ pSim, float* __restrict__ pDiv,
                            float* __restrict__ pMet) {
    __shared__ __align__(16) float As[KC][ASLD];
    __shared__ __align__(16) float Bs[KC][ASLD];
    int b = blockIdx.x, t = threadIdx.x;
    if (b < 16) {
        gemm64_partial(pooled, W_sim, pSim, 128, (b >> 3) * 64, (b & 7) * KB, b & 7, t, As, Bs);
    } else if (b < 32) {
        int id = b - 16;
        gemm64_partial(pooled, W_div, pDiv, 128, (id >> 3) * 64, (id & 7) * KB, id & 7, t, As, Bs);
    } else {
        int id = b - 32;
        gemm64_partial(pooled, W_met, pMet, 1024, (id >> 3) * 64, (id & 7) * KB, id & 7, t, As, Bs);
    }
}

// ---------------- K4: fewshot (blocks 0..63) + con partial GEMM (64..95) ----------------
__global__ void tail_fewshot_con(const float* __restrict__ pMet,
                                 const float* __restrict__ b_met,
                                 const float* __restrict__ W_con,
                                 float* __restrict__ pCon,
                                 const float* __restrict__ pooled,
                                 const float* __restrict__ supF,
                                 const int* __restrict__ labels,
                                 const int* __restrict__ supL,
                                 float* __restrict__ out_fsp) {
    __shared__ __align__(16) float As[KC][ASLD];
    __shared__ __align__(16) float Bs[KC][ASLD];
    __shared__ float ps[HH];
    __shared__ float sims[SUP];
    __shared__ float pred[NCLS];
    int blk = blockIdx.x, t = threadIdx.x;

    if (blk >= BB) {
        // con partial: A = combined meta (sum 8 partials + b_met), W = W_con [256,1024]
        int id = blk - BB;                 // 0..31
        int n0 = (id >> 3) * 64, ks = id & 7, k0 = ks * KB;
        int tm = t >> 4, tn = t & 15;
        int lr = t >> 2, lq = t & 3;
        float acc[4][4] = {};
        for (int kc = 0; kc < KB; kc += KC) {
            int ka = k0 + kc + lq * 4;
            float4 s0 = *(const float4*)(b_met + ka);
            float4 s1 = *(const float4*)(b_met + ka + 16);
#pragma unroll
            for (int p = 0; p < KSPLIT; ++p) {
                float4 v0 = *(const float4*)(pMet + ((size_t)p * 64 + lr) * HH + ka);
                float4 v1 = *(const float4*)(pMet + ((size_t)p * 64 + lr) * HH + ka + 16);
                s0.x += v0.x; s0.y += v0.y; s0.z += v0.z; s0.w += v0.w;
                s1.x += v1.x; s1.y += v1.y; s1.z += v1.z; s1.w += v1.w;
            }
            float4 w0 = *(const float4*)(W_con + (size_t)(n0 + lr) * HH + ka);
            float4 w1 = *(const float4*)(W_con + (size_t)(n0 + lr) * HH + ka + 16);
            As[lq * 4 + 0][lr] = s0.x; As[lq * 4 + 1][lr] = s0.y;
            As[lq * 4 + 2][lr] = s0.z; As[lq * 4 + 3][lr] = s0.w;
            As[16 + lq * 4 + 0][lr] = s1.x; As[16 + lq * 4 + 1][lr] = s1.y;
            As[16 + lq * 4 + 2][lr] = s1.z; As[16 + lq * 4 + 3][lr] = s1.w;
            Bs[lq * 4 + 0][lr] = w0.x; Bs[lq * 4 + 1][lr] = w0.y;
            Bs[lq * 4 + 2][lr] = w0.z; Bs[lq * 4 + 3][lr] = w0.w;
            Bs[16 + lq * 4 + 0][lr] = w1.x; Bs[16 + lq * 4 + 1][lr] = w1.y;
            Bs[16 + lq * 4 + 2][lr] = w1.z; Bs[16 + lq * 4 + 3][lr] = w1.w;
            __syncthreads();
#pragma unroll
            for (int k = 0; k < KC; ++k) {
                float4 a4 = *(const float4*)&As[k][tm * 4];
                float4 b4 = *(const float4*)&Bs[k][tn * 4];
                acc[0][0] += a4.x * b4.x; acc[0][1] += a4.x * b4.y;
                acc[0][2] += a4.x * b4.z; acc[0][3] += a4.x * b4.w;
                acc[1][0] += a4.y * b4.x; acc[1][1] += a4.y * b4.y;
                acc[1][2] += a4.y * b4.z; acc[1][3] += a4.y * b4.w;
                acc[2][0] += a4.z * b4.x; acc[2][1] += a4.z * b4.y;
                acc[2][2] += a4.z * b4.z; acc[2][3] += a4.z * b4.w;
                acc[3][0] += a4.w * b4.x; acc[3][1] += a4.w * b4.y;
                acc[3][2] += a4.w * b4.z; acc[3][3] += a4.w * b4.w;
            }
            __syncthreads();
        }
#pragma unroll
        for (int i = 0; i < 4; ++i) {
            float4 o = make_float4(acc[i][0], acc[i][1], acc[i][2], acc[i][3]);
            *(float4*)(pCon + ((size_t)ks * 64 + tm * 4 + i) * 256 + n0 + tn * 4) = o;
        }
        return;
    }

    // ---- fewshot path ----
    int b = blk;
    ((float4*)ps)[t] = ((const float4*)(pooled + (size_t)b * HH))[t];
    __syncthreads();

    int wave = t >> 6, lane = t & 63;
    for (int j = wave; j < SUP; j += 4) {
        const float* row = (j < BB) ? (pooled + (size_t)j * HH)
                                    : (supF + (size_t)j * HH);
        float s = 0.f;
#pragma unroll
        for (int q = 0; q < 16; ++q) {
            int h = lane + q * 64;
            s += ps[h] * row[h];
        }
        for (int off = 32; off; off >>= 1) s += __shfl_down(s, off);
        if (lane == 0) sims[j] = s;
    }
    __syncthreads();

    if (t == 0) {
        float vals[KFS]; int idx[KFS];
        for (int i = 0; i < KFS; ++i) {
            float best = -3.4e38f; int bi = 0;
            for (int j = 0; j < SUP; ++j) {
                bool taken = false;
                for (int p = 0; p < i; ++p) taken = taken || (idx[p] == j);
                if (!taken && sims[j] > best) { best = sims[j]; bi = j; }
            }
            vals[i] = best; idx[i] = bi;
        }
        float mx = vals[0];
        for (int i = 1; i < KFS; ++i) mx = fmaxf(mx, vals[i]);
        float e[KFS], sum = 0.f;
        for (int i = 0; i < KFS; ++i) { e[i] = __expf(vals[i] - mx); sum += e[i]; }
        float p0 = 0.f, p1 = 0.f, p2 = 0.f;
        for (int i = 0; i < KFS; ++i) {
            int j = idx[i];
            int lab = (j < BB) ? labels[j] : supL[j];
            float wv = e[i] / sum;
            if (lab == 0) p0 += wv;
            else if (lab == 1) p1 += wv;
            else if (lab == 2) p2 += wv;
        }
        pred[0] = p0; pred[1] = p1; pred[2] = p2;
    }
    __syncthreads();

    float p[NCLS] = {pred[0], pred[1], pred[2]};
    for (int i = t; i < SS * NCLS; i += 256) {
        int c = i - (i / NCLS) * NCLS;
        out_fsp[(size_t)b * SS * NCLS + i] = p[c];
    }
}

// ---------------- K5: combine partials + bias -> final sim/div/con ----------------
__global__ void combine(const float* __restrict__ pSim, const float* __restrict__ b_sim,
                        const float* __restrict__ pDiv, const float* __restrict__ b_div,
                        const float* __restrict__ pCon, const float* __restrict__ b_con,
                        float* __restrict__ out_sim, float* __restrict__ out_div,
                        float* __restrict__ out_con) {
    int gid = blockIdx.x * 256 + threadIdx.x;
    if (gid < 8192) {
        float s = b_sim[gid & 127];
#pragma unroll
        for (int p = 0; p < KSPLIT; ++p) s += pSim[p * 8192 + gid];
        out_sim[gid] = s;
    } else if (gid < 16384) {
        int i = gid - 8192;
        float s = b_div[i & 127];
#pragma unroll
        for (int p = 0; p < KSPLIT; ++p) s += pDiv[p * 8192 + i];
        out_div[i] = s;
    } else {
        int i = gid - 16384;
        float s = b_con[i & 255];
#pragma unroll
        for (int p = 0; p < KSPLIT; ++p) s += pCon[p * 16384 + i];
        out_con[i] = s;
    }
}

extern "C" void kernel_launch(void* const* d_in, const int* in_sizes, int n_in,
                              void* d_out, int out_size, void* d_ws, size_t ws_size,
                              hipStream_t stream) {
    const float* hs    = (const float*)d_in[0];   // [64,512,1024]
    const int*   lab   = (const int*)  d_in[1];   // [64]
    const float* supF  = (const float*)d_in[2];   // [100,1024]
    const int*   supL  = (const int*)  d_in[3];   // [100]
    const float* W_sim = (const float*)d_in[4];   // [128,1024]
    const float* b_sim = (const float*)d_in[5];
    const float* W_div = (const float*)d_in[6];   // [128,1024]
    const float* b_div = (const float*)d_in[7];
    const float* W_met = (const float*)d_in[8];   // [1024,1024]
    const float* b_met = (const float*)d_in[9];
    const float* W_con = (const float*)d_in[10];  // [256,1024]
    const float* b_con = (const float*)d_in[11];

    float* out = (float*)d_out;
    float* out_fsp  = out;                 // [64,512,3]  = 98304
    float* out_sim  = out + 98304;         // [64,128]    = 8192
    float* out_div  = out + 106496;        // [64,128]    = 8192
    float* out_con  = out + 114688;        // [64,256]    = 16384

    float* ws     = (float*)d_ws;
    float* part   = ws;                              // 32*64*1024 = 2M floats
    float* pooled = part + (size_t)SEG * BB * HH;    // 64K
    float* pSim   = pooled + BB * HH;                // 8*64*128 = 64K
    float* pDiv   = pSim + KSPLIT * BB * 128;        // 64K
    float* pMet   = pDiv + KSPLIT * BB * 128;        // 8*64*1024 = 512K
    float* pCon   = pMet + (size_t)KSPLIT * BB * HH; // 8*64*256 = 128K

    pool_partial<<<BB * SEG, 256, 0, stream>>>(hs, part);
    pool_reduce <<<BB,       256, 0, stream>>>(part, pooled);
    lin_partial <<<160,      256, 0, stream>>>(pooled, W_sim, W_div, W_met, pSim, pDiv, pMet);
    tail_fewshot_con<<<96,   256, 0, stream>>>(pMet, b_met, W_con, pCon,
                                               pooled, supF, lab, supL, out_fsp);
    combine<<<128, 256, 0, stream>>>(pSim, b_sim, pDiv, b_div, pCon, b_con,
                                     out_sim, out_div, out_con);
}